// Round 3
// baseline (138.129 us; speedup 1.0000x reference)
//
#include <hip/hip_runtime.h>

// B=16, T=512, D=384, target_len=4096. x: f32, durations: int32 (sniffed
// f32/i64/i32/i16), out: f32.
// R14 post-mortem: NO DATA — container failed twice (infra), kernel never
// measured. R15 = re-run of R14's experiment (single defensive tweak:
// dropped __launch_bounds__ min-waves suffix).
// Standing theory: fills (63us ws + ~16us out, harness-fixed) + build ~5us
// + EXPAND ~35us. Expand moves 113 MB mandatory -> 18us floor, runs at
// ~3.3 TB/s vs fill's 6.4. Structural diff vs fill: 4096 blocks x 24KB
// runs = ~1280 interleaved short write streams -> DRAM page thrash.
// R15: RPB 16->64. 1024 blocks (4/CU, single-shot residency), each writes
// one contiguous 96KB run; idx loads hoisted; gathers 8-deep. Build and
// fallback byte-identical to R13.
// Predicted: expand ~35->~22us, total ~108-114us. If neutral -> harness
// floor, evaluate ROOFLINE next round.
#define B_   16
#define T_   512
#define TLEN 4096
#define XC   96    // 16B f32 chunks per row (384*4/16)
#define RPE  64    // rows per expand block (16 passes x 4 rows, 96KB run)
#define SENT 0xFFFFu

typedef float f4v __attribute__((ext_vector_type(4)));
typedef unsigned short u16x8 __attribute__((ext_vector_type(8)));

__device__ __forceinline__ int sniff_dur(const unsigned int* __restrict__ durw,
                                         int e) {
    // dtype sniff on first 32 words (deterministic, uniform; values 0..15)
    int f32ok = 1, i64ok = 1, i32ok = 1, i16ok = 1;
    #pragma unroll
    for (int k = 0; k < 32; ++k) {
        unsigned w = durw[k];
        f32ok &= (int)((w == 0u) | ((w >= 0x3F800000u) & (w <= 0x41700000u)));
        i64ok &= (int)((k & 1) ? (w == 0u) : (w <= 15u));
        i32ok &= (int)(w <= 15u);
        i16ok &= (int)(((w & 0xFFFFu) <= 15u) & ((w >> 16) <= 15u));
    }
    int v;
    if (f32ok)      v = (int)__uint_as_float(durw[e]);
    else if (i64ok) v = (int)durw[e * 2];
    else if (i32ok) v = (int)durw[e];
    else if (i16ok) v = (int)((durw[e >> 1] >> (16 * (e & 1))) & 0xFFFFu);
    else            v = (int)durw[e];
    return v;
}

// Kernel 1: per-batch scan, then search-based inversion -> idx map
// (u16, 0xFFFF = pad). Each thread owns 8 contiguous output positions,
// finds the covering token via 10-step binary search on LDS cum, walks
// forward (idx advances <=1 per position since dur>=1), and stores all
// 8 u16 as one 16B coalesced write. Map written exactly once.
__global__ __launch_bounds__(T_) void lr_build_idx(const unsigned int* __restrict__ durw,
                                                   unsigned short* __restrict__ idx) {
    __shared__ int s[T_];
    const int b = blockIdx.x;
    const int t = threadIdx.x;

    int v = sniff_dur(durw, b * T_ + t);
    s[t] = v < 1 ? 1 : v;
    __syncthreads();
    for (int off = 1; off < T_; off <<= 1) {
        int add = (t >= off) ? s[t - off] : 0;
        __syncthreads();
        s[t] += add;
        __syncthreads();
    }
    // s[] now holds inclusive cum; last loop iteration ended with a barrier.

    // Inversion: positions [8t, 8t+8). Find first i with s[i] > j0.
    const int j0 = t * 8;
    int lo = 0, hi = T_;
    #pragma unroll
    for (int k = 0; k < 10; ++k) {   // 513 outcomes -> 10 iters (lo==hi after)
        int mid = (lo + hi) >> 1;    // mid <= 511, never reads s[512]
        if (s[mid] > j0) hi = mid; else lo = mid + 1;
    }
    int i = lo;                      // idx(j0), or T_ if j0 >= total
    u16x8 pack;
    #pragma unroll
    for (int q = 0; q < 8; ++q) {
        const int j = j0 + q;
        // cum strictly increasing (dur>=1) -> idx advances 0 or 1 per j
        if (i < T_ && s[i] <= j) ++i;
        pack[q] = (i < T_) ? (unsigned short)i : (unsigned short)SENT;
    }
    *reinterpret_cast<u16x8*>(idx + b * TLEN + j0) = pack;  // 16B aligned
}

// Kernel 2: search-free gather-stream, long-run edition.
// 1024 blocks x 384 threads (4 blocks/CU, single-shot residency).
// Each block owns 64 consecutive rows = one contiguous 96KB output run.
// 96 lanes per row, 4 rows per pass, 16 passes; gathers batched 8-deep.
__global__ __launch_bounds__(384) void lr_expand_idx(const f4v* __restrict__ x,
                                                     const unsigned short* __restrict__ idx,
                                                     f4v* __restrict__ out) {
    const int tid = threadIdx.x;
    const int sub = tid / XC;              // 0..3
    const int col = tid - sub * XC;        // 0..95
    const int base = blockIdx.x * RPE;     // 64-aligned; 4096 rows/batch, no straddle
    const int b = base >> 12;
    const int row0 = base + sub;

    // Phase 1: hoist all 16 idx loads (independent, broadcast across lanes)
    unsigned iv[16];
    #pragma unroll
    for (int p = 0; p < 16; ++p) iv[p] = idx[row0 + p * 4];

    // Phases 2+3: two groups of {8 gathers in flight -> 8 stores}.
    // Store addr = base*96 + p*384 + tid -> linear in tid, contiguous in p:
    // the block emits one unbroken 96KB write run (vs 24KB runs in R13;
    // theory: short interleaved streams caused DRAM page thrash).
    #pragma unroll
    for (int g = 0; g < 2; ++g) {
        f4v v[8];
        #pragma unroll
        for (int q = 0; q < 8; ++q) {
            const int p = g * 8 + q;
            v[q] = (f4v){0.f, 0.f, 0.f, 0.f};
            if (iv[p] != SENT) v[q] = x[(b * T_ + (int)iv[p]) * XC + col];
        }
        #pragma unroll
        for (int q = 0; q < 8; ++q) {
            const int p = g * 8 + q;
            out[(size_t)(row0 + p * 4) * XC + col] = v[q];
        }
    }
}

// ---- Fallback (ws too small for idx map): cum + binary search ----
__global__ __launch_bounds__(T_) void lr_scan(const unsigned int* __restrict__ durw,
                                              int* __restrict__ cum) {
    __shared__ int s[T_];
    const int b = blockIdx.x;
    const int t = threadIdx.x;
    int v = sniff_dur(durw, b * T_ + t);
    s[t] = v < 1 ? 1 : v;
    __syncthreads();
    for (int off = 1; off < T_; off <<= 1) {
        int add = (t >= off) ? s[t - off] : 0;
        __syncthreads();
        s[t] += add;
        __syncthreads();
    }
    cum[b * T_ + t] = s[t];
}

__global__ __launch_bounds__(384) void lr_expand(const f4v* __restrict__ x,
                                                 const int* __restrict__ cum,
                                                 f4v* __restrict__ out) {
    __shared__ int sc[T_];
    const int tid  = threadIdx.x;
    const int row0 = blockIdx.x * 32;
    const int b    = row0 >> 12;
    for (int i = tid; i < T_; i += 384) sc[i] = cum[b * T_ + i];
    __syncthreads();
    const int total = sc[T_ - 1];
    const int sub = tid / XC;
    const int col = tid - sub * XC;
    #pragma unroll
    for (int p = 0; p < 8; ++p) {
        const int row = row0 + p * 4 + sub;
        const int t   = row & (TLEN - 1);
        f4v val = (f4v){0.f, 0.f, 0.f, 0.f};
        if (t < total) {
            int lo = 0, hi = T_;
            #pragma unroll
            for (int i = 0; i < 10; ++i) {   // 513 outcomes -> 10 iters
                int mid = (lo + hi) >> 1;
                if (sc[mid] > t) hi = mid; else lo = mid + 1;
            }
            const int idx2 = lo > (T_ - 1) ? (T_ - 1) : lo;
            val = x[(b * T_ + idx2) * XC + col];
        }
        out[(size_t)row * XC + col] = val;
    }
}

extern "C" void kernel_launch(void* const* d_in, const int* in_sizes, int n_in,
                              void* d_out, int out_size, void* d_ws, size_t ws_size,
                              hipStream_t stream) {
    // d_in[0]=x, d_in[1]=durations, d_in[2]=target_len (shapes fixed).
    const f4v* x = (const f4v*)d_in[0];
    const unsigned int* durw = (const unsigned int*)d_in[1];

    if (ws_size >= (size_t)(B_ * TLEN * 2)) {         // 128 KB idx map
        unsigned short* idx = (unsigned short*)d_ws;
        lr_build_idx<<<B_, T_, 0, stream>>>(durw, idx);
        lr_expand_idx<<<(B_ * TLEN) / RPE, 384, 0, stream>>>(x, idx, (f4v*)d_out);
    } else {                                          // 32 KB cum fallback
        int* cum = (int*)d_ws;
        lr_scan<<<B_, T_, 0, stream>>>(durw, cum);
        lr_expand<<<(B_ * TLEN) / 32, 384, 0, stream>>>(x, cum, (f4v*)d_out);
    }
}

// Round 4
// 128.637 us; speedup vs baseline: 1.0738x; 1.0738x over previous
//
#include <hip/hip_runtime.h>

// B=16, T=512, D=384, target_len=4096. x: f32, durations: int32 (sniffed
// f32/i64/i32/i16), out: f32.
// R15 post-mortem: long-run expand (RPE=64, 1024 blocks) REGRESSED
// 127.2->138.1. DRAM-page-thrash theory dead; revert to R13 expand
// (RPB=16, 4096 blocks, best measured).
// Revised theory: expand gathers ~100MB logical reads of a 12.6MB x
// working set. 12.6MB > 4MiB per-XCD L2 and blocks round-robin across
// XCDs -> every XCD touches all 16 batches -> L2 thrash -> reads served
// by L3/fabric, contending with the 100MB HBM write stream (~200MB at
// shared ~6.4 TB/s ~= 31us, matches observed ~35us).
// R16: ONE variable vs R13 — XCD-aware bijective swizzle (T1). 4096 =
// 8*512 exactly: swz=(bid&7)*512+(bid>>3). Each XCD owns 512 consecutive
// row-blocks = exactly 2 batches -> 1.57MB gather set << 4MiB L2.
// Predicted: expand ~35->~18-22us, total ~108-114us; expand FETCH_SIZE
// down, TCC_HIT up. If neutral -> expand at floor, declare ROOFLINE.
#define B_   16
#define T_   512
#define TLEN 4096
#define XC   96    // 16B f32 chunks per row (384*4/16)
#define RPB  16    // rows per expand block (4 passes x 4 rows)
#define SENT 0xFFFFu

typedef float f4v __attribute__((ext_vector_type(4)));
typedef unsigned short u16x8 __attribute__((ext_vector_type(8)));

__device__ __forceinline__ int sniff_dur(const unsigned int* __restrict__ durw,
                                         int e) {
    // dtype sniff on first 32 words (deterministic, uniform; values 0..15)
    int f32ok = 1, i64ok = 1, i32ok = 1, i16ok = 1;
    #pragma unroll
    for (int k = 0; k < 32; ++k) {
        unsigned w = durw[k];
        f32ok &= (int)((w == 0u) | ((w >= 0x3F800000u) & (w <= 0x41700000u)));
        i64ok &= (int)((k & 1) ? (w == 0u) : (w <= 15u));
        i32ok &= (int)(w <= 15u);
        i16ok &= (int)(((w & 0xFFFFu) <= 15u) & ((w >> 16) <= 15u));
    }
    int v;
    if (f32ok)      v = (int)__uint_as_float(durw[e]);
    else if (i64ok) v = (int)durw[e * 2];
    else if (i32ok) v = (int)durw[e];
    else if (i16ok) v = (int)((durw[e >> 1] >> (16 * (e & 1))) & 0xFFFFu);
    else            v = (int)durw[e];
    return v;
}

// Kernel 1: per-batch scan, then search-based inversion -> idx map
// (u16, 0xFFFF = pad). Each thread owns 8 contiguous output positions,
// finds the covering token via 10-step binary search on LDS cum, walks
// forward (idx advances <=1 per position since dur>=1), and stores all
// 8 u16 as one 16B coalesced write. Map written exactly once.
__global__ __launch_bounds__(T_) void lr_build_idx(const unsigned int* __restrict__ durw,
                                                   unsigned short* __restrict__ idx) {
    __shared__ int s[T_];
    const int b = blockIdx.x;
    const int t = threadIdx.x;

    int v = sniff_dur(durw, b * T_ + t);
    s[t] = v < 1 ? 1 : v;
    __syncthreads();
    for (int off = 1; off < T_; off <<= 1) {
        int add = (t >= off) ? s[t - off] : 0;
        __syncthreads();
        s[t] += add;
        __syncthreads();
    }
    // s[] now holds inclusive cum; last loop iteration ended with a barrier.

    // Inversion: positions [8t, 8t+8). Find first i with s[i] > j0.
    const int j0 = t * 8;
    int lo = 0, hi = T_;
    #pragma unroll
    for (int k = 0; k < 10; ++k) {   // 513 outcomes -> 10 iters (lo==hi after)
        int mid = (lo + hi) >> 1;    // mid <= 511, never reads s[512]
        if (s[mid] > j0) hi = mid; else lo = mid + 1;
    }
    int i = lo;                      // idx(j0), or T_ if j0 >= total
    u16x8 pack;
    #pragma unroll
    for (int q = 0; q < 8; ++q) {
        const int j = j0 + q;
        // cum strictly increasing (dur>=1) -> idx advances 0 or 1 per j
        if (i < T_ && s[i] <= j) ++i;
        pack[q] = (i < T_) ? (unsigned short)i : (unsigned short)SENT;
    }
    *reinterpret_cast<u16x8*>(idx + b * TLEN + j0) = pack;  // 16B aligned
}

// Kernel 2: search-free gather-stream, R13 structure + XCD swizzle.
// 4096 blocks x 384 threads; 96 lanes per row, 4 rows per pass, 4 passes.
// Bijective chunked swizzle (4096 = 8 XCDs x 512): each XCD owns 512
// consecutive row-blocks = exactly 2 batches -> 1.57MB x working set per
// XCD L2 (vs 12.6MB unswizzled thrash).
__global__ __launch_bounds__(384) void lr_expand_idx(const f4v* __restrict__ x,
                                                     const unsigned short* __restrict__ idx,
                                                     f4v* __restrict__ out) {
    const int tid = threadIdx.x;
    const int sub = tid / XC;              // 0..3
    const int col = tid - sub * XC;        // 0..95
    const int bid = blockIdx.x;
    const int swz = ((bid & 7) << 9) + (bid >> 3);   // (bid%8)*512 + bid/8
    const int row0 = swz * RPB + sub;
    const int b = (swz * RPB) >> 12;       // 4096 rows/batch, no straddle

    // Phase 1: all idx loads (independent, broadcast across the row's lanes)
    unsigned iv[4];
    #pragma unroll
    for (int p = 0; p < 4; ++p) iv[p] = idx[row0 + p * 4];

    // Phase 2: all gathers (XCD-local L2-hot x rows) — 4 chains in flight
    f4v v[4];
    #pragma unroll
    for (int p = 0; p < 4; ++p) {
        v[p] = (f4v){0.f, 0.f, 0.f, 0.f};
        if (iv[p] != SENT) v[p] = x[(b * T_ + (int)iv[p]) * XC + col];
    }

    // Phase 3: all stores (plain stores, L2 writeback path)
    #pragma unroll
    for (int p = 0; p < 4; ++p)
        out[(size_t)(row0 + p * 4) * XC + col] = v[p];
}

// ---- Fallback (ws too small for idx map): cum + binary search ----
__global__ __launch_bounds__(T_) void lr_scan(const unsigned int* __restrict__ durw,
                                              int* __restrict__ cum) {
    __shared__ int s[T_];
    const int b = blockIdx.x;
    const int t = threadIdx.x;
    int v = sniff_dur(durw, b * T_ + t);
    s[t] = v < 1 ? 1 : v;
    __syncthreads();
    for (int off = 1; off < T_; off <<= 1) {
        int add = (t >= off) ? s[t - off] : 0;
        __syncthreads();
        s[t] += add;
        __syncthreads();
    }
    cum[b * T_ + t] = s[t];
}

__global__ __launch_bounds__(384) void lr_expand(const f4v* __restrict__ x,
                                                 const int* __restrict__ cum,
                                                 f4v* __restrict__ out) {
    __shared__ int sc[T_];
    const int tid  = threadIdx.x;
    const int row0 = blockIdx.x * 32;
    const int b    = row0 >> 12;
    for (int i = tid; i < T_; i += 384) sc[i] = cum[b * T_ + i];
    __syncthreads();
    const int total = sc[T_ - 1];
    const int sub = tid / XC;
    const int col = tid - sub * XC;
    #pragma unroll
    for (int p = 0; p < 8; ++p) {
        const int row = row0 + p * 4 + sub;
        const int t   = row & (TLEN - 1);
        f4v val = (f4v){0.f, 0.f, 0.f, 0.f};
        if (t < total) {
            int lo = 0, hi = T_;
            #pragma unroll
            for (int i = 0; i < 10; ++i) {   // 513 outcomes -> 10 iters
                int mid = (lo + hi) >> 1;
                if (sc[mid] > t) hi = mid; else lo = mid + 1;
            }
            const int idx2 = lo > (T_ - 1) ? (T_ - 1) : lo;
            val = x[(b * T_ + idx2) * XC + col];
        }
        out[(size_t)row * XC + col] = val;
    }
}

extern "C" void kernel_launch(void* const* d_in, const int* in_sizes, int n_in,
                              void* d_out, int out_size, void* d_ws, size_t ws_size,
                              hipStream_t stream) {
    // d_in[0]=x, d_in[1]=durations, d_in[2]=target_len (shapes fixed).
    const f4v* x = (const f4v*)d_in[0];
    const unsigned int* durw = (const unsigned int*)d_in[1];

    if (ws_size >= (size_t)(B_ * TLEN * 2)) {         // 128 KB idx map
        unsigned short* idx = (unsigned short*)d_ws;
        lr_build_idx<<<B_, T_, 0, stream>>>(durw, idx);
        lr_expand_idx<<<(B_ * TLEN) / RPB, 384, 0, stream>>>(x, idx, (f4v*)d_out);
    } else {                                          // 32 KB cum fallback
        int* cum = (int*)d_ws;
        lr_scan<<<B_, T_, 0, stream>>>(durw, cum);
        lr_expand<<<(B_ * TLEN) / 32, 384, 0, stream>>>(x, cum, (f4v*)d_out);
    }
}